// Round 13
// baseline (272.812 us; speedup 1.0000x reference)
//
#include <hip/hip_runtime.h>
#include <math.h>

#define F 128
#define RBF 16
#define NATOMS 50000
#define NPAIRS 600000
#define NBLK 196   // ceil(NATOMS/256)

typedef float f32x4 __attribute__((ext_vector_type(4)));
typedef short s16x8 __attribute__((ext_vector_type(8)));

// fast softplus: max(x,0) + ln(1+exp(-|x|))  (__expf/__logf = v_exp/v_log based)
__device__ __forceinline__ float sp(float x) {
    return fmaxf(x, 0.f) + __logf(1.f + __expf(-fabsf(x)));
}
// f2bf RNE bit ops (asm cvt_pk was -9%: blocks scheduler — keep plain bit ops)
__device__ __forceinline__ unsigned short f2bf(float x) {
    unsigned u = __float_as_uint(x);
    u += 0x7FFFu + ((u >> 16) & 1u);
    return (unsigned short)(u >> 16);
}
__device__ __forceinline__ float bf2f(unsigned short u) {
    return __uint_as_float(((unsigned)u) << 16);
}

// ---------------------------------------------------------------------------
// Weight prepack: fp32 [128][128] row-major -> bf16 fragment order
// ---------------------------------------------------------------------------
__global__ __launch_bounds__(256) void prep_w_k(
    const float* __restrict__ Wi, const float* __restrict__ Wj, const float* __restrict__ Wv,
    const float* __restrict__ iW1, const float* __restrict__ iW2,
    const float* __restrict__ oW1, const float* __restrict__ oW2,
    short* __restrict__ wpack)
{
    int o = blockIdx.x * 256 + threadIdx.x;
    if (o >= 13 * 16384) return;
    int mat = o >> 14;
    int rem = o & 16383;
    int j = rem & 7;
    int lane = (rem >> 3) & 63;
    int nt = (rem >> 9) & 7;
    int kc = rem >> 12;
    int k = kc * 32 + ((lane >> 4) << 3) + j;
    int n = nt * 16 + (lane & 15);
    const float* src;
    if (mat == 0) src = Wi;
    else if (mat == 1) src = Wj;
    else if (mat == 2) src = Wv;
    else if (mat < 6) src = iW1 + (size_t)(mat - 3) * 16384;
    else if (mat < 9) src = iW2 + (size_t)(mat - 6) * 16384;
    else if (mat < 11) src = oW1 + (size_t)(mat - 9) * 16384;
    else src = oW2 + (size_t)(mat - 11) * 16384;
    wpack[o] = (short)f2bf(src[(size_t)k * F + n]);
}

// A fragment: row l&15 (+wave base), k = kc*32 + (l>>4)*8 + 0..7, from global fp32
template <int PRE>
__device__ __forceinline__ s16x8 load_a_frag(const float* __restrict__ in,
                                             int row, int nrows, int kc, int cg)
{
    s16x8 a;
    if (row < nrows) {
        const float* p = in + (size_t)row * F + kc * 32 + cg * 8;
        float4 x0 = *(const float4*)p;
        float4 x1 = *(const float4*)(p + 4);
        if (PRE) {
            x0.x = sp(x0.x); x0.y = sp(x0.y); x0.z = sp(x0.z); x0.w = sp(x0.w);
            x1.x = sp(x1.x); x1.y = sp(x1.y); x1.z = sp(x1.z); x1.w = sp(x1.w);
        }
        a[0] = f2bf(x0.x); a[1] = f2bf(x0.y); a[2] = f2bf(x0.z); a[3] = f2bf(x0.w);
        a[4] = f2bf(x1.x); a[5] = f2bf(x1.y); a[6] = f2bf(x1.z); a[7] = f2bf(x1.w);
    } else {
#pragma unroll
        for (int i = 0; i < 8; ++i) a[i] = 0;
    }
    return a;
}

// ---------------------------------------------------------------------------
// MFMA GEMM (head): [nrows,128] x [128,128], column-split wave pairs.
// Block = 256 thr = 2 row-groups x 2 col-half waves; 32 rows/block.
// ---------------------------------------------------------------------------
template <int PRE, int POST, int DUAL>
__global__ __launch_bounds__(256) void mgemm_k(
    const float* __restrict__ in, const short* __restrict__ wpA,
    const float* __restrict__ bA, float* __restrict__ outA,
    const short* __restrict__ wpB, const float* __restrict__ bB,
    unsigned short* __restrict__ outB, int nrows)
{
    const int lane = threadIdx.x & 63;
    const int wv = threadIdx.x >> 6;
    const int grp = wv >> 1, half = wv & 1;
    const int r0 = blockIdx.x * 32 + grp * 16;
    const int cl = lane & 15, cg = lane >> 4;
    const int ntb = half * 4;

    s16x8 afr[4];
#pragma unroll
    for (int kc = 0; kc < 4; ++kc) afr[kc] = load_a_frag<PRE>(in, r0 + cl, nrows, kc, cg);

    f32x4 accA[4], accB[4];
#pragma unroll
    for (int n = 0; n < 4; ++n) {
        accA[n] = (f32x4){0.f, 0.f, 0.f, 0.f};
        accB[n] = (f32x4){0.f, 0.f, 0.f, 0.f};
    }

#pragma unroll
    for (int kc = 0; kc < 4; ++kc) {
        const s16x8* bpA = (const s16x8*)wpA + (size_t)(kc * 8 + ntb) * 64 + lane;
#pragma unroll
        for (int n = 0; n < 4; ++n) {
            s16x8 b = bpA[n * 64];
            accA[n] = __builtin_amdgcn_mfma_f32_16x16x32_bf16(afr[kc], b, accA[n], 0, 0, 0);
        }
        if (DUAL) {
            const s16x8* bpB = (const s16x8*)wpB + (size_t)(kc * 8 + ntb) * 64 + lane;
#pragma unroll
            for (int n = 0; n < 4; ++n) {
                s16x8 b = bpB[n * 64];
                accB[n] = __builtin_amdgcn_mfma_f32_16x16x32_bf16(afr[kc], b, accB[n], 0, 0, 0);
            }
        }
    }

#pragma unroll
    for (int n = 0; n < 4; ++n) {
        const int col = (ntb + n) * 16 + cl;
        const float ba = bA[col];
        const float bb = DUAL ? bB[col] : 0.f;
#pragma unroll
        for (int q = 0; q < 4; ++q) {
            const int row = r0 + cg * 4 + q;
            if (row < nrows) {
                const size_t o = (size_t)row * F + col;
                float val = accA[n][q] + ba;
                if (POST == 1) val = sp(val);
                outA[o] = val;
                if (DUAL) outB[o] = f2bf(sp(accB[n][q] + bb));
            }
        }
    }
}

// ---------------------------------------------------------------------------
// Fused tail (round-6 configuration — best measured: 107 us) + s_setprio(T5)
// around the MFMA cluster: independent blocks at different phases on each CU
// (attn-like setting where setprio measured +4-7%; lockstep-GEMM case was null).
// ---------------------------------------------------------------------------
__device__ __forceinline__ void gemm_half(const short* __restrict__ wp, int lane, int ntb,
                                          const s16x8 afr[4], f32x4 acc[4])
{
#pragma unroll
    for (int n = 0; n < 4; ++n) acc[n] = (f32x4){0.f, 0.f, 0.f, 0.f};
    __builtin_amdgcn_s_setprio(1);
#pragma unroll
    for (int kc = 0; kc < 4; ++kc) {
        const s16x8* bp = (const s16x8*)wp + (size_t)(kc * 8 + ntb) * 64 + lane;
#pragma unroll
        for (int n = 0; n < 4; ++n) {
            s16x8 b = bp[n * 64];
            acc[n] = __builtin_amdgcn_mfma_f32_16x16x32_bf16(afr[kc], b, acc[n], 0, 0, 0);
        }
    }
    __builtin_amdgcn_s_setprio(0);
}

template <int FIRST>
__device__ __forceinline__ void residual_half(
    const float* __restrict__ u, f32x4 xreg[4],
    unsigned short* __restrict__ S, unsigned short* __restrict__ H,
    const short* __restrict__ wp1, const float* __restrict__ b1,
    const short* __restrict__ wp2, const float* __restrict__ b2,
    int r0, int nrows, int lane, int cl, int cg, int ntb)
{
    s16x8 afr[4];
    if (FIRST) {
#pragma unroll
        for (int kc = 0; kc < 4; ++kc) afr[kc] = load_a_frag<1>(u, r0 + cl, nrows, kc, cg);
    } else {
#pragma unroll
        for (int kc = 0; kc < 4; ++kc)
            afr[kc] = *(const s16x8*)(S + cl * 144 + kc * 32 + cg * 8);
    }
    f32x4 acc[4];
    gemm_half(wp1, lane, ntb, afr, acc);
    // h = sp(acc + b1) -> H (bf16, C/D positions = A-layout for gemm2)
#pragma unroll
    for (int n = 0; n < 4; ++n) {
        const int col = (ntb + n) * 16 + cl;
        const float bb = b1[col];
#pragma unroll
        for (int q = 0; q < 4; ++q)
            H[(cg * 4 + q) * 144 + col] = f2bf(sp(acc[n][q] + bb));
    }
    __syncthreads();   // barrier 1: H complete; all S-reads complete
#pragma unroll
    for (int kc = 0; kc < 4; ++kc)
        afr[kc] = *(const s16x8*)(H + cl * 144 + kc * 32 + cg * 8);
    gemm_half(wp2, lane, ntb, afr, acc);
    // x += h@W2 + b2 (registers); spx = sp(x) -> S for next stage
#pragma unroll
    for (int n = 0; n < 4; ++n) {
        const int col = (ntb + n) * 16 + cl;
        const float bb = b2[col];
#pragma unroll
        for (int q = 0; q < 4; ++q) {
            float xv = xreg[n][q] + acc[n][q] + bb;
            xreg[n][q] = xv;
            S[(cg * 4 + q) * 144 + col] = f2bf(sp(xv));
        }
    }
    __syncthreads();   // barrier 2: S (spx) complete; H-reads complete
}

__global__ __launch_bounds__(256, 4) void fused_tail_k(
    const float* __restrict__ u, const float* __restrict__ emb,
    const float* __restrict__ gate,
    const short* __restrict__ wpI1, const float* __restrict__ ib1,
    const short* __restrict__ wpI2, const float* __restrict__ ib2,
    const short* __restrict__ wpWv, const float* __restrict__ bvv,
    const short* __restrict__ wpO1, const float* __restrict__ ob1,
    const short* __restrict__ wpO2, const float* __restrict__ ob2,
    const float* __restrict__ Wo, const float* __restrict__ bo,
    float* __restrict__ vout, float* __restrict__ pred, int nrows)
{
    __shared__ unsigned short Sb[2][16 * 144];
    __shared__ unsigned short Hb[2][16 * 144];
    const int lane = threadIdx.x & 63;
    const int wv = threadIdx.x >> 6;
    const int grp = wv >> 1, half = wv & 1;
    const int r0 = blockIdx.x * 32 + grp * 16;
    const int cl = lane & 15, cg = lane >> 4;
    const int ntb = half * 4;
    unsigned short* S = Sb[grp];
    unsigned short* H = Hb[grp];

    // x in registers, C/D layout: xreg[n][q] = x[r0+cg*4+q][(ntb+n)*16+cl]
    f32x4 xreg[4];
#pragma unroll
    for (int n = 0; n < 4; ++n) {
        const int col = (ntb + n) * 16 + cl;
#pragma unroll
        for (int q = 0; q < 4; ++q) {
            const int row = r0 + cg * 4 + q;
            xreg[n][q] = (row < nrows) ? u[(size_t)row * F + col] : 0.f;
        }
    }

    // 3 interaction residual blocks (stage 1 reads A-frags straight from global)
    residual_half<1>(u, xreg, S, H, wpI1, ib1, wpI2, ib2,
                     r0, nrows, lane, cl, cg, ntb);
    for (int k = 1; k < 3; ++k)
        residual_half<0>(u, xreg, S, H,
                         wpI1 + (size_t)k * 16384, ib1 + (size_t)k * F,
                         wpI2 + (size_t)k * 16384, ib2 + (size_t)k * F,
                         r0, nrows, lane, cl, cg, ntb);

    // v = gate*sp(emb) + sp(x)@Wv + bv ; x = v ; write v
    {
        s16x8 afr[4];
#pragma unroll
        for (int kc = 0; kc < 4; ++kc)
            afr[kc] = *(const s16x8*)(S + cl * 144 + kc * 32 + cg * 8);
        f32x4 acc[4];
        gemm_half(wpWv, lane, ntb, afr, acc);
        __syncthreads();   // partner's S-reads done before we overwrite S
#pragma unroll
        for (int n = 0; n < 4; ++n) {
            const int col = (ntb + n) * 16 + cl;
            const float bb = bvv[col];
            const float gt = gate[col];
#pragma unroll
            for (int q = 0; q < 4; ++q) {
                const int row = r0 + cg * 4 + q;
                float val = acc[n][q] + bb;
                if (row < nrows) {
                    const size_t o = (size_t)row * F + col;
                    val += gt * sp(emb[o]);
                    vout[o] = val;
                }
                xreg[n][q] = val;
                S[(cg * 4 + q) * 144 + col] = f2bf(sp(val));
            }
        }
        __syncthreads();
    }

    // 2 output residual blocks
    for (int k = 0; k < 2; ++k)
        residual_half<0>(u, xreg, S, H,
                         wpO1 + (size_t)k * 16384, ob1 + (size_t)k * F,
                         wpO2 + (size_t)k * 16384, ob2 + (size_t)k * F,
                         r0, nrows, lane, cl, cg, ntb);

    // pred = x @ Wo + bo : per-wave partials over its 4 nt, combine via LDS
    {
        float2 wo[4];
#pragma unroll
        for (int n = 0; n < 4; ++n)
            wo[n] = *(const float2*)(Wo + (size_t)((ntb + n) * 16 + cl) * 2);
        float* sc = (float*)S;   // reuse S as fp32 scratch (all spx reads done)
#pragma unroll
        for (int q = 0; q < 4; ++q) {
            float a0 = xreg[0][q] * wo[0].x + xreg[1][q] * wo[1].x
                     + xreg[2][q] * wo[2].x + xreg[3][q] * wo[3].x;
            float a1 = xreg[0][q] * wo[0].y + xreg[1][q] * wo[1].y
                     + xreg[2][q] * wo[2].y + xreg[3][q] * wo[3].y;
#pragma unroll
            for (int m = 1; m < 16; m <<= 1) {
                a0 += __shfl_xor(a0, m);
                a1 += __shfl_xor(a1, m);
            }
            if (cl == 0) {
                sc[half * 32 + (cg * 4 + q) * 2 + 0] = a0;
                sc[half * 32 + (cg * 4 + q) * 2 + 1] = a1;
            }
        }
        __syncthreads();
        if (half == 0 && lane < 16) {
            const int row = r0 + lane;
            if (row < nrows) {
                pred[(size_t)row * 2 + 0] = sc[lane * 2 + 0] + sc[32 + lane * 2 + 0] + bo[0];
                pred[(size_t)row * 2 + 1] = sc[lane * 2 + 1] + sc[32 + lane * 2 + 1] + bo[1];
            }
        }
    }
}

// ---------------------------------------------------------------------------
// CSR build: hist + 3-phase coalesced scan + scatter (counts zeroed by memset)
// scatter packs (j,p) into one int2 so the gather does a single 8B index load.
// ---------------------------------------------------------------------------
__global__ void hist_k(const int* __restrict__ idx_i, int* __restrict__ counts)
{
    int p = blockIdx.x * blockDim.x + threadIdx.x;
    if (p < NPAIRS) atomicAdd(&counts[idx_i[p]], 1);
}

// phase 1: per-256-chunk sums (coalesced)
__global__ __launch_bounds__(256) void scan1_k(
    const int* __restrict__ counts, int* __restrict__ bsum)
{
    __shared__ int red[256];
    const int t = threadIdx.x;
    const int i = blockIdx.x * 256 + t;
    red[t] = (i < NATOMS) ? counts[i] : 0;
    __syncthreads();
#pragma unroll
    for (int s = 128; s > 0; s >>= 1) {
        if (t < s) red[t] += red[t + s];
        __syncthreads();
    }
    if (t == 0) bsum[blockIdx.x] = red[0];
}

// phase 2: exclusive scan of the NBLK block sums (single block)
__global__ __launch_bounds__(256) void scan2_k(
    const int* __restrict__ bsum, int* __restrict__ bbase, int* __restrict__ offsets)
{
    __shared__ int sh[256];
    const int t = threadIdx.x;
    const int v = (t < NBLK) ? bsum[t] : 0;
    sh[t] = v;
    __syncthreads();
#pragma unroll
    for (int s = 1; s < 256; s <<= 1) {
        int add = (t >= s) ? sh[t - s] : 0;
        __syncthreads();
        sh[t] += add;
        __syncthreads();
    }
    if (t < NBLK) bbase[t] = sh[t] - v;   // exclusive
    if (t == 0) offsets[NATOMS] = NPAIRS;
}

// phase 3: within-chunk exclusive scan + base -> offsets & cursor
__global__ __launch_bounds__(256) void scan3_k(
    const int* __restrict__ counts, const int* __restrict__ bbase,
    int* __restrict__ offsets, int* __restrict__ cursor)
{
    __shared__ int sh[256];
    const int t = threadIdx.x;
    const int i = blockIdx.x * 256 + t;
    const int v = (i < NATOMS) ? counts[i] : 0;
    sh[t] = v;
    __syncthreads();
#pragma unroll
    for (int s = 1; s < 256; s <<= 1) {
        int add = (t >= s) ? sh[t - s] : 0;
        __syncthreads();
        sh[t] += add;
        __syncthreads();
    }
    if (i < NATOMS) {
        const int off = bbase[blockIdx.x] + sh[t] - v;
        offsets[i] = off;
        cursor[i] = off;
    }
}

__global__ void scatter_k(const int* __restrict__ idx_i, const int* __restrict__ idx_j,
                          int* __restrict__ cursor, int2* __restrict__ jplist)
{
    int p = blockIdx.x * blockDim.x + threadIdx.x;
    if (p < NPAIRS) {
        int pos = atomicAdd(&cursor[idx_i[p]], 1);
        jplist[pos] = make_int2(idx_j[p], p);
    }
}

// ---------------------------------------------------------------------------
// Gather: one wave per atom, 2 features per lane, register accumulation.
// 16-deep batches of packed int2 (j,p): mean degree 12 -> most waves finish in
// ONE batch; serial chain = offsets -> jp -> mj/fij. SGPR bases via
// readfirstlane.
// ---------------------------------------------------------------------------
__device__ __forceinline__ void gpair(const float* __restrict__ fp,
                                      const float* wg0, const float* wg1,
                                      float& g0, float& g1)
{
    float4 A = ((const float4*)fp)[0], B = ((const float4*)fp)[1];
    float4 C = ((const float4*)fp)[2], D = ((const float4*)fp)[3];
    g0 = A.x*wg0[0] + A.y*wg0[1] + A.z*wg0[2] + A.w*wg0[3]
       + B.x*wg0[4] + B.y*wg0[5] + B.z*wg0[6] + B.w*wg0[7]
       + C.x*wg0[8] + C.y*wg0[9] + C.z*wg0[10] + C.w*wg0[11]
       + D.x*wg0[12] + D.y*wg0[13] + D.z*wg0[14] + D.w*wg0[15];
    g1 = A.x*wg1[0] + A.y*wg1[1] + A.z*wg1[2] + A.w*wg1[3]
       + B.x*wg1[4] + B.y*wg1[5] + B.z*wg1[6] + B.w*wg1[7]
       + C.x*wg1[8] + C.y*wg1[9] + C.z*wg1[10] + C.w*wg1[11]
       + D.x*wg1[12] + D.y*wg1[13] + D.z*wg1[14] + D.w*wg1[15];
}

__global__ __launch_bounds__(256) void gather_k(
    const unsigned short* __restrict__ mj, const float* __restrict__ fij,
    const int2* __restrict__ jplist, const int* __restrict__ offsets,
    const float* __restrict__ Wg, float* __restrict__ u)
{
    const int lane = threadIdx.x & 63;
    const int atom = blockIdx.x * 4 + (threadIdx.x >> 6);
    const int f0 = lane * 2;

    float wg0[16], wg1[16];
#pragma unroll
    for (int r = 0; r < 16; ++r) {
        float2 w = *(const float2*)(Wg + r * F + f0);
        wg0[r] = w.x; wg1[r] = w.y;
    }

    const int k0 = offsets[atom], k1 = offsets[atom + 1];
    float acc0 = 0.f, acc1 = 0.f;

    for (int k = k0; k < k1; k += 16) {
        // clamped 16-wide packed index load (wave-uniform addresses)
        int2 jp[16];
#pragma unroll
        for (int t = 0; t < 16; ++t) {
            const int kk = (k + t < k1) ? (k + t) : (k1 - 1);
            jp[t] = jplist[kk];
        }
        // all 16 mj rows in flight with SGPR bases
        unsigned m[16];
        const float* fp[16];
#pragma unroll
        for (int t = 0; t < 16; ++t) {
            const int js = __builtin_amdgcn_readfirstlane(jp[t].x);
            const int ps = __builtin_amdgcn_readfirstlane(jp[t].y);
            m[t] = *(const unsigned*)(mj + (size_t)js * F + f0);
            fp[t] = fij + (size_t)ps * RBF;
        }
        // compute 16 pairs, masking pads
#pragma unroll
        for (int t = 0; t < 16; ++t) {
            float g0, g1;
            gpair(fp[t], wg0, wg1, g0, g1);
            if (k + t >= k1) { g0 = 0.f; g1 = 0.f; }
            acc0 += bf2f((unsigned short)(m[t] & 0xFFFF)) * g0;
            acc1 += bf2f((unsigned short)(m[t] >> 16))    * g1;
        }
    }

    float2* up = (float2*)(u + (size_t)atom * F + f0);
    float2 old = *up;
    old.x += acc0; old.y += acc1;
    *up = old;
}

extern "C" void kernel_launch(void* const* d_in, const int* in_sizes, int n_in,
                              void* d_out, int out_size, void* d_ws, size_t ws_size,
                              hipStream_t stream)
{
    const float* emb   = (const float*)d_in[0];
    const float* fij   = (const float*)d_in[1];
    const int*   pidx  = (const int*)d_in[2];
    const float* Wg    = (const float*)d_in[3];
    const float* Wi    = (const float*)d_in[4];
    const float* bi    = (const float*)d_in[5];
    const float* Wj    = (const float*)d_in[6];
    const float* bj    = (const float*)d_in[7];
    const float* Wv    = (const float*)d_in[8];
    const float* bv    = (const float*)d_in[9];
    const float* gate  = (const float*)d_in[10];
    const float* iW1   = (const float*)d_in[11];
    const float* ib1   = (const float*)d_in[12];
    const float* iW2   = (const float*)d_in[13];
    const float* ib2   = (const float*)d_in[14];
    const float* oW1   = (const float*)d_in[15];
    const float* ob1   = (const float*)d_in[16];
    const float* oW2   = (const float*)d_in[17];
    const float* ob2   = (const float*)d_in[18];
    const float* Wo    = (const float*)d_in[19];
    const float* bo    = (const float*)d_in[20];

    const int* idx_i = pidx;
    const int* idx_j = pidx + NPAIRS;

    float* outp = (float*)d_out;
    float* pred = outp;                        // [N,2]
    float* v    = outp + (size_t)NATOMS * 2;   // [N,128]

    const size_t NF = (size_t)NATOMS * F;
    float* u = (float*)d_ws;                          // [N,F] fp32
    unsigned short* mj = (unsigned short*)(u + NF);   // [N,F] bf16
    short* wpack = (short*)(mj + NF);                 // 13*16384 bf16
    int* counts   = (int*)(wpack + 13 * 16384);
    int* offsets  = counts + NATOMS;
    int* cursor   = offsets + NATOMS + 1;
    int2* jplist  = (int2*)(cursor + NATOMS);         // 2*NPAIRS ints
    int* bsum     = (int*)(jplist + NPAIRS);
    int* bbase    = bsum + NBLK;

    const short* wpWi = wpack;
    const short* wpWj = wpack + 1 * 16384;
    const short* wpWv = wpack + 2 * 16384;
    const short* wpI1 = wpack + 3 * 16384;   // 3 mats
    const short* wpI2 = wpack + 6 * 16384;   // 3 mats
    const short* wpO1 = wpack + 9 * 16384;   // 2 mats
    const short* wpO2 = wpack + 11 * 16384;  // 2 mats

    // weight prepack + CSR build
    prep_w_k<<<(13 * 16384 + 255) / 256, 256, 0, stream>>>(Wi, Wj, Wv, iW1, iW2, oW1, oW2, wpack);
    hipMemsetAsync(counts, 0, NATOMS * sizeof(int), stream);
    hist_k<<<(NPAIRS + 255) / 256, 256, 0, stream>>>(idx_i, counts);
    scan1_k<<<NBLK, 256, 0, stream>>>(counts, bsum);
    scan2_k<<<1, 256, 0, stream>>>(bsum, bbase, offsets);
    scan3_k<<<NBLK, 256, 0, stream>>>(counts, bbase, offsets, cursor);
    scatter_k<<<(NPAIRS + 255) / 256, 256, 0, stream>>>(idx_i, idx_j, cursor, jplist);

    // u = sp(sp(emb)@Wi+bi); mj = bf16(sp(sp(emb)@Wj+bj))   (32 rows/block)
    mgemm_k<1, 1, 1><<<(NATOMS + 31) / 32, 256, 0, stream>>>(
        emb, wpWi, bi, u, wpWj, bj, mj, NATOMS);

    // u[i] += mj[j] * (fij @ Wg), one wave per atom, 16-deep packed batches
    gather_k<<<(NATOMS + 3) / 4, 256, 0, stream>>>(
        mj, fij, jplist, offsets, Wg, u);

    // fused tail: 3 int res + Wv combine + 2 out res + pred (32 rows/block)
    fused_tail_k<<<(NATOMS + 31) / 32, 256, 0, stream>>>(
        u, emb, gate,
        wpI1, ib1, wpI2, ib2,
        wpWv, bv,
        wpO1, ob1, wpO2, ob2,
        Wo, bo, v, pred, NATOMS);
}

// Round 14
// 256.865 us; speedup vs baseline: 1.0621x; 1.0621x over previous
//
#include <hip/hip_runtime.h>
#include <math.h>

#define F 128
#define RBF 16
#define NATOMS 50000
#define NPAIRS 600000
#define NBLK 196   // ceil(NATOMS/256)

typedef float f32x4 __attribute__((ext_vector_type(4)));
typedef short s16x8 __attribute__((ext_vector_type(8)));

// fast softplus: max(x,0) + ln(1+exp(-|x|))  (__expf/__logf = v_exp/v_log based)
__device__ __forceinline__ float sp(float x) {
    return fmaxf(x, 0.f) + __logf(1.f + __expf(-fabsf(x)));
}
// f2bf RNE bit ops (asm cvt_pk was -9%: blocks scheduler — keep plain bit ops)
__device__ __forceinline__ unsigned short f2bf(float x) {
    unsigned u = __float_as_uint(x);
    u += 0x7FFFu + ((u >> 16) & 1u);
    return (unsigned short)(u >> 16);
}
__device__ __forceinline__ float bf2f(unsigned short u) {
    return __uint_as_float(((unsigned)u) << 16);
}

// ---------------------------------------------------------------------------
// Weight prepack: fp32 [128][128] row-major -> bf16 fragment order
// ---------------------------------------------------------------------------
__global__ __launch_bounds__(256) void prep_w_k(
    const float* __restrict__ Wi, const float* __restrict__ Wj, const float* __restrict__ Wv,
    const float* __restrict__ iW1, const float* __restrict__ iW2,
    const float* __restrict__ oW1, const float* __restrict__ oW2,
    short* __restrict__ wpack)
{
    int o = blockIdx.x * 256 + threadIdx.x;
    if (o >= 13 * 16384) return;
    int mat = o >> 14;
    int rem = o & 16383;
    int j = rem & 7;
    int lane = (rem >> 3) & 63;
    int nt = (rem >> 9) & 7;
    int kc = rem >> 12;
    int k = kc * 32 + ((lane >> 4) << 3) + j;
    int n = nt * 16 + (lane & 15);
    const float* src;
    if (mat == 0) src = Wi;
    else if (mat == 1) src = Wj;
    else if (mat == 2) src = Wv;
    else if (mat < 6) src = iW1 + (size_t)(mat - 3) * 16384;
    else if (mat < 9) src = iW2 + (size_t)(mat - 6) * 16384;
    else if (mat < 11) src = oW1 + (size_t)(mat - 9) * 16384;
    else src = oW2 + (size_t)(mat - 11) * 16384;
    wpack[o] = (short)f2bf(src[(size_t)k * F + n]);
}

// A fragment: row l&15 (+wave base), k = kc*32 + (l>>4)*8 + 0..7, from global fp32
template <int PRE>
__device__ __forceinline__ s16x8 load_a_frag(const float* __restrict__ in,
                                             int row, int nrows, int kc, int cg)
{
    s16x8 a;
    if (row < nrows) {
        const float* p = in + (size_t)row * F + kc * 32 + cg * 8;
        float4 x0 = *(const float4*)p;
        float4 x1 = *(const float4*)(p + 4);
        if (PRE) {
            x0.x = sp(x0.x); x0.y = sp(x0.y); x0.z = sp(x0.z); x0.w = sp(x0.w);
            x1.x = sp(x1.x); x1.y = sp(x1.y); x1.z = sp(x1.z); x1.w = sp(x1.w);
        }
        a[0] = f2bf(x0.x); a[1] = f2bf(x0.y); a[2] = f2bf(x0.z); a[3] = f2bf(x0.w);
        a[4] = f2bf(x1.x); a[5] = f2bf(x1.y); a[6] = f2bf(x1.z); a[7] = f2bf(x1.w);
    } else {
#pragma unroll
        for (int i = 0; i < 8; ++i) a[i] = 0;
    }
    return a;
}

// ---------------------------------------------------------------------------
// MFMA GEMM (head): [nrows,128] x [128,128], column-split wave pairs.
// Block = 256 thr = 2 row-groups x 2 col-half waves; 32 rows/block.
// ---------------------------------------------------------------------------
template <int PRE, int POST, int DUAL>
__global__ __launch_bounds__(256) void mgemm_k(
    const float* __restrict__ in, const short* __restrict__ wpA,
    const float* __restrict__ bA, float* __restrict__ outA,
    const short* __restrict__ wpB, const float* __restrict__ bB,
    unsigned short* __restrict__ outB, int nrows)
{
    const int lane = threadIdx.x & 63;
    const int wv = threadIdx.x >> 6;
    const int grp = wv >> 1, half = wv & 1;
    const int r0 = blockIdx.x * 32 + grp * 16;
    const int cl = lane & 15, cg = lane >> 4;
    const int ntb = half * 4;

    s16x8 afr[4];
#pragma unroll
    for (int kc = 0; kc < 4; ++kc) afr[kc] = load_a_frag<PRE>(in, r0 + cl, nrows, kc, cg);

    f32x4 accA[4], accB[4];
#pragma unroll
    for (int n = 0; n < 4; ++n) {
        accA[n] = (f32x4){0.f, 0.f, 0.f, 0.f};
        accB[n] = (f32x4){0.f, 0.f, 0.f, 0.f};
    }

#pragma unroll
    for (int kc = 0; kc < 4; ++kc) {
        const s16x8* bpA = (const s16x8*)wpA + (size_t)(kc * 8 + ntb) * 64 + lane;
#pragma unroll
        for (int n = 0; n < 4; ++n) {
            s16x8 b = bpA[n * 64];
            accA[n] = __builtin_amdgcn_mfma_f32_16x16x32_bf16(afr[kc], b, accA[n], 0, 0, 0);
        }
        if (DUAL) {
            const s16x8* bpB = (const s16x8*)wpB + (size_t)(kc * 8 + ntb) * 64 + lane;
#pragma unroll
            for (int n = 0; n < 4; ++n) {
                s16x8 b = bpB[n * 64];
                accB[n] = __builtin_amdgcn_mfma_f32_16x16x32_bf16(afr[kc], b, accB[n], 0, 0, 0);
            }
        }
    }

#pragma unroll
    for (int n = 0; n < 4; ++n) {
        const int col = (ntb + n) * 16 + cl;
        const float ba = bA[col];
        const float bb = DUAL ? bB[col] : 0.f;
#pragma unroll
        for (int q = 0; q < 4; ++q) {
            const int row = r0 + cg * 4 + q;
            if (row < nrows) {
                const size_t o = (size_t)row * F + col;
                float val = accA[n][q] + ba;
                if (POST == 1) val = sp(val);
                outA[o] = val;
                if (DUAL) outB[o] = f2bf(sp(accB[n][q] + bb));
            }
        }
    }
}

// ---------------------------------------------------------------------------
// Fused tail (round-6 structure + s_setprio(T5) around MFMA — measured win:
// tail 107 -> ~97 us in round 13; independent blocks at different phases).
// Block = 256 thr = 2 row-groups x 2 col-half waves; 32 rows/block.
// ---------------------------------------------------------------------------
__device__ __forceinline__ void gemm_half(const short* __restrict__ wp, int lane, int ntb,
                                          const s16x8 afr[4], f32x4 acc[4])
{
#pragma unroll
    for (int n = 0; n < 4; ++n) acc[n] = (f32x4){0.f, 0.f, 0.f, 0.f};
    __builtin_amdgcn_s_setprio(1);
#pragma unroll
    for (int kc = 0; kc < 4; ++kc) {
        const s16x8* bp = (const s16x8*)wp + (size_t)(kc * 8 + ntb) * 64 + lane;
#pragma unroll
        for (int n = 0; n < 4; ++n) {
            s16x8 b = bp[n * 64];
            acc[n] = __builtin_amdgcn_mfma_f32_16x16x32_bf16(afr[kc], b, acc[n], 0, 0, 0);
        }
    }
    __builtin_amdgcn_s_setprio(0);
}

template <int FIRST>
__device__ __forceinline__ void residual_half(
    const float* __restrict__ u, f32x4 xreg[4],
    unsigned short* __restrict__ S, unsigned short* __restrict__ H,
    const short* __restrict__ wp1, const float* __restrict__ b1,
    const short* __restrict__ wp2, const float* __restrict__ b2,
    int r0, int nrows, int lane, int cl, int cg, int ntb)
{
    s16x8 afr[4];
    if (FIRST) {
#pragma unroll
        for (int kc = 0; kc < 4; ++kc) afr[kc] = load_a_frag<1>(u, r0 + cl, nrows, kc, cg);
    } else {
#pragma unroll
        for (int kc = 0; kc < 4; ++kc)
            afr[kc] = *(const s16x8*)(S + cl * 144 + kc * 32 + cg * 8);
    }
    f32x4 acc[4];
    gemm_half(wp1, lane, ntb, afr, acc);
    // h = sp(acc + b1) -> H (bf16, C/D positions = A-layout for gemm2)
#pragma unroll
    for (int n = 0; n < 4; ++n) {
        const int col = (ntb + n) * 16 + cl;
        const float bb = b1[col];
#pragma unroll
        for (int q = 0; q < 4; ++q)
            H[(cg * 4 + q) * 144 + col] = f2bf(sp(acc[n][q] + bb));
    }
    __syncthreads();   // barrier 1: H complete; all S-reads complete
#pragma unroll
    for (int kc = 0; kc < 4; ++kc)
        afr[kc] = *(const s16x8*)(H + cl * 144 + kc * 32 + cg * 8);
    gemm_half(wp2, lane, ntb, afr, acc);
    // x += h@W2 + b2 (registers); spx = sp(x) -> S for next stage
#pragma unroll
    for (int n = 0; n < 4; ++n) {
        const int col = (ntb + n) * 16 + cl;
        const float bb = b2[col];
#pragma unroll
        for (int q = 0; q < 4; ++q) {
            float xv = xreg[n][q] + acc[n][q] + bb;
            xreg[n][q] = xv;
            S[(cg * 4 + q) * 144 + col] = f2bf(sp(xv));
        }
    }
    __syncthreads();   // barrier 2: S (spx) complete; H-reads complete
}

__global__ __launch_bounds__(256, 4) void fused_tail_k(
    const float* __restrict__ u, const float* __restrict__ emb,
    const float* __restrict__ gate,
    const short* __restrict__ wpI1, const float* __restrict__ ib1,
    const short* __restrict__ wpI2, const float* __restrict__ ib2,
    const short* __restrict__ wpWv, const float* __restrict__ bvv,
    const short* __restrict__ wpO1, const float* __restrict__ ob1,
    const short* __restrict__ wpO2, const float* __restrict__ ob2,
    const float* __restrict__ Wo, const float* __restrict__ bo,
    float* __restrict__ vout, float* __restrict__ pred, int nrows)
{
    __shared__ unsigned short Sb[2][16 * 144];
    __shared__ unsigned short Hb[2][16 * 144];
    const int lane = threadIdx.x & 63;
    const int wv = threadIdx.x >> 6;
    const int grp = wv >> 1, half = wv & 1;
    const int r0 = blockIdx.x * 32 + grp * 16;
    const int cl = lane & 15, cg = lane >> 4;
    const int ntb = half * 4;
    unsigned short* S = Sb[grp];
    unsigned short* H = Hb[grp];

    // x in registers, C/D layout: xreg[n][q] = x[r0+cg*4+q][(ntb+n)*16+cl]
    f32x4 xreg[4];
#pragma unroll
    for (int n = 0; n < 4; ++n) {
        const int col = (ntb + n) * 16 + cl;
#pragma unroll
        for (int q = 0; q < 4; ++q) {
            const int row = r0 + cg * 4 + q;
            xreg[n][q] = (row < nrows) ? u[(size_t)row * F + col] : 0.f;
        }
    }

    // 3 interaction residual blocks (stage 1 reads A-frags straight from global)
    residual_half<1>(u, xreg, S, H, wpI1, ib1, wpI2, ib2,
                     r0, nrows, lane, cl, cg, ntb);
    for (int k = 1; k < 3; ++k)
        residual_half<0>(u, xreg, S, H,
                         wpI1 + (size_t)k * 16384, ib1 + (size_t)k * F,
                         wpI2 + (size_t)k * 16384, ib2 + (size_t)k * F,
                         r0, nrows, lane, cl, cg, ntb);

    // v = gate*sp(emb) + sp(x)@Wv + bv ; x = v ; write v
    {
        s16x8 afr[4];
#pragma unroll
        for (int kc = 0; kc < 4; ++kc)
            afr[kc] = *(const s16x8*)(S + cl * 144 + kc * 32 + cg * 8);
        f32x4 acc[4];
        gemm_half(wpWv, lane, ntb, afr, acc);
        __syncthreads();   // partner's S-reads done before we overwrite S
#pragma unroll
        for (int n = 0; n < 4; ++n) {
            const int col = (ntb + n) * 16 + cl;
            const float bb = bvv[col];
            const float gt = gate[col];
#pragma unroll
            for (int q = 0; q < 4; ++q) {
                const int row = r0 + cg * 4 + q;
                float val = acc[n][q] + bb;
                if (row < nrows) {
                    const size_t o = (size_t)row * F + col;
                    val += gt * sp(emb[o]);
                    vout[o] = val;
                }
                xreg[n][q] = val;
                S[(cg * 4 + q) * 144 + col] = f2bf(sp(val));
            }
        }
        __syncthreads();
    }

    // 2 output residual blocks
    for (int k = 0; k < 2; ++k)
        residual_half<0>(u, xreg, S, H,
                         wpO1 + (size_t)k * 16384, ob1 + (size_t)k * F,
                         wpO2 + (size_t)k * 16384, ob2 + (size_t)k * F,
                         r0, nrows, lane, cl, cg, ntb);

    // pred = x @ Wo + bo : per-wave partials over its 4 nt, combine via LDS
    {
        float2 wo[4];
#pragma unroll
        for (int n = 0; n < 4; ++n)
            wo[n] = *(const float2*)(Wo + (size_t)((ntb + n) * 16 + cl) * 2);
        float* sc = (float*)S;   // reuse S as fp32 scratch (all spx reads done)
#pragma unroll
        for (int q = 0; q < 4; ++q) {
            float a0 = xreg[0][q] * wo[0].x + xreg[1][q] * wo[1].x
                     + xreg[2][q] * wo[2].x + xreg[3][q] * wo[3].x;
            float a1 = xreg[0][q] * wo[0].y + xreg[1][q] * wo[1].y
                     + xreg[2][q] * wo[2].y + xreg[3][q] * wo[3].y;
#pragma unroll
            for (int m = 1; m < 16; m <<= 1) {
                a0 += __shfl_xor(a0, m);
                a1 += __shfl_xor(a1, m);
            }
            if (cl == 0) {
                sc[half * 32 + (cg * 4 + q) * 2 + 0] = a0;
                sc[half * 32 + (cg * 4 + q) * 2 + 1] = a1;
            }
        }
        __syncthreads();
        if (half == 0 && lane < 16) {
            const int row = r0 + lane;
            if (row < nrows) {
                pred[(size_t)row * 2 + 0] = sc[lane * 2 + 0] + sc[32 + lane * 2 + 0] + bo[0];
                pred[(size_t)row * 2 + 1] = sc[lane * 2 + 1] + sc[32 + lane * 2 + 1] + bo[1];
            }
        }
    }
}

// ---------------------------------------------------------------------------
// CSR build: hist + 3-phase coalesced scan + scatter (counts zeroed by memset)
// ---------------------------------------------------------------------------
__global__ void hist_k(const int* __restrict__ idx_i, int* __restrict__ counts)
{
    int p = blockIdx.x * blockDim.x + threadIdx.x;
    if (p < NPAIRS) atomicAdd(&counts[idx_i[p]], 1);
}

// phase 1: per-256-chunk sums (coalesced)
__global__ __launch_bounds__(256) void scan1_k(
    const int* __restrict__ counts, int* __restrict__ bsum)
{
    __shared__ int red[256];
    const int t = threadIdx.x;
    const int i = blockIdx.x * 256 + t;
    red[t] = (i < NATOMS) ? counts[i] : 0;
    __syncthreads();
#pragma unroll
    for (int s = 128; s > 0; s >>= 1) {
        if (t < s) red[t] += red[t + s];
        __syncthreads();
    }
    if (t == 0) bsum[blockIdx.x] = red[0];
}

// phase 2: exclusive scan of the NBLK block sums (single block)
__global__ __launch_bounds__(256) void scan2_k(
    const int* __restrict__ bsum, int* __restrict__ bbase, int* __restrict__ offsets)
{
    __shared__ int sh[256];
    const int t = threadIdx.x;
    const int v = (t < NBLK) ? bsum[t] : 0;
    sh[t] = v;
    __syncthreads();
#pragma unroll
    for (int s = 1; s < 256; s <<= 1) {
        int add = (t >= s) ? sh[t - s] : 0;
        __syncthreads();
        sh[t] += add;
        __syncthreads();
    }
    if (t < NBLK) bbase[t] = sh[t] - v;   // exclusive
    if (t == 0) offsets[NATOMS] = NPAIRS;
}

// phase 3: within-chunk exclusive scan + base -> offsets & cursor
__global__ __launch_bounds__(256) void scan3_k(
    const int* __restrict__ counts, const int* __restrict__ bbase,
    int* __restrict__ offsets, int* __restrict__ cursor)
{
    __shared__ int sh[256];
    const int t = threadIdx.x;
    const int i = blockIdx.x * 256 + t;
    const int v = (i < NATOMS) ? counts[i] : 0;
    sh[t] = v;
    __syncthreads();
#pragma unroll
    for (int s = 1; s < 256; s <<= 1) {
        int add = (t >= s) ? sh[t - s] : 0;
        __syncthreads();
        sh[t] += add;
        __syncthreads();
    }
    if (i < NATOMS) {
        const int off = bbase[blockIdx.x] + sh[t] - v;
        offsets[i] = off;
        cursor[i] = off;
    }
}

__global__ void scatter_k(const int* __restrict__ idx_i, const int* __restrict__ idx_j,
                          int* __restrict__ cursor, int* __restrict__ plist,
                          int* __restrict__ jlist)
{
    int p = blockIdx.x * blockDim.x + threadIdx.x;
    if (p < NPAIRS) {
        int pos = atomicAdd(&cursor[idx_i[p]], 1);
        plist[pos] = p;
        jlist[pos] = idx_j[p];
    }
}

// ---------------------------------------------------------------------------
// Gather (round-12 configuration — best measured ~84 us): one wave per atom,
// 2 features per lane, register accumulation; 8-deep clamped+masked batches,
// uniform SGPR bases via readfirstlane. (16-deep packed int2 measured +15 us:
// always-16 gpair compute wastes VALU on the ~15% of atoms with degree<=8.)
// ---------------------------------------------------------------------------
__device__ __forceinline__ void gpair(const float* __restrict__ fp,
                                      const float* wg0, const float* wg1,
                                      float& g0, float& g1)
{
    float4 A = ((const float4*)fp)[0], B = ((const float4*)fp)[1];
    float4 C = ((const float4*)fp)[2], D = ((const float4*)fp)[3];
    g0 = A.x*wg0[0] + A.y*wg0[1] + A.z*wg0[2] + A.w*wg0[3]
       + B.x*wg0[4] + B.y*wg0[5] + B.z*wg0[6] + B.w*wg0[7]
       + C.x*wg0[8] + C.y*wg0[9] + C.z*wg0[10] + C.w*wg0[11]
       + D.x*wg0[12] + D.y*wg0[13] + D.z*wg0[14] + D.w*wg0[15];
    g1 = A.x*wg1[0] + A.y*wg1[1] + A.z*wg1[2] + A.w*wg1[3]
       + B.x*wg1[4] + B.y*wg1[5] + B.z*wg1[6] + B.w*wg1[7]
       + C.x*wg1[8] + C.y*wg1[9] + C.z*wg1[10] + C.w*wg1[11]
       + D.x*wg1[12] + D.y*wg1[13] + D.z*wg1[14] + D.w*wg1[15];
}

__global__ __launch_bounds__(256) void gather_k(
    const unsigned short* __restrict__ mj, const float* __restrict__ fij,
    const int* __restrict__ jlist, const int* __restrict__ plist,
    const int* __restrict__ offsets, const float* __restrict__ Wg,
    float* __restrict__ u)
{
    const int lane = threadIdx.x & 63;
    const int atom = blockIdx.x * 4 + (threadIdx.x >> 6);
    const int f0 = lane * 2;

    float wg0[16], wg1[16];
#pragma unroll
    for (int r = 0; r < 16; ++r) {
        float2 w = *(const float2*)(Wg + r * F + f0);
        wg0[r] = w.x; wg1[r] = w.y;
    }

    const int k0 = offsets[atom], k1 = offsets[atom + 1];
    float acc0 = 0.f, acc1 = 0.f;

    for (int k = k0; k < k1; k += 8) {
        // clamped 8-wide index load (wave-uniform addresses)
        int jv[8], pv[8];
#pragma unroll
        for (int t = 0; t < 8; ++t) {
            const int kk = (k + t < k1) ? (k + t) : (k1 - 1);
            jv[t] = jlist[kk];
            pv[t] = plist[kk];
        }
        // all 8 mj rows in flight with SGPR bases
        unsigned m[8];
        const float* fp[8];
#pragma unroll
        for (int t = 0; t < 8; ++t) {
            const int js = __builtin_amdgcn_readfirstlane(jv[t]);
            const int ps = __builtin_amdgcn_readfirstlane(pv[t]);
            m[t] = *(const unsigned*)(mj + (size_t)js * F + f0);
            fp[t] = fij + (size_t)ps * RBF;
        }
        // compute 8 pairs, masking pads
#pragma unroll
        for (int t = 0; t < 8; ++t) {
            float g0, g1;
            gpair(fp[t], wg0, wg1, g0, g1);
            if (k + t >= k1) { g0 = 0.f; g1 = 0.f; }
            acc0 += bf2f((unsigned short)(m[t] & 0xFFFF)) * g0;
            acc1 += bf2f((unsigned short)(m[t] >> 16))    * g1;
        }
    }

    float2* up = (float2*)(u + (size_t)atom * F + f0);
    float2 old = *up;
    old.x += acc0; old.y += acc1;
    *up = old;
}

extern "C" void kernel_launch(void* const* d_in, const int* in_sizes, int n_in,
                              void* d_out, int out_size, void* d_ws, size_t ws_size,
                              hipStream_t stream)
{
    const float* emb   = (const float*)d_in[0];
    const float* fij   = (const float*)d_in[1];
    const int*   pidx  = (const int*)d_in[2];
    const float* Wg    = (const float*)d_in[3];
    const float* Wi    = (const float*)d_in[4];
    const float* bi    = (const float*)d_in[5];
    const float* Wj    = (const float*)d_in[6];
    const float* bj    = (const float*)d_in[7];
    const float* Wv    = (const float*)d_in[8];
    const float* bv    = (const float*)d_in[9];
    const float* gate  = (const float*)d_in[10];
    const float* iW1   = (const float*)d_in[11];
    const float* ib1   = (const float*)d_in[12];
    const float* iW2   = (const float*)d_in[13];
    const float* ib2   = (const float*)d_in[14];
    const float* oW1   = (const float*)d_in[15];
    const float* ob1   = (const float*)d_in[16];
    const float* oW2   = (const float*)d_in[17];
    const float* ob2   = (const float*)d_in[18];
    const float* Wo    = (const float*)d_in[19];
    const float* bo    = (const float*)d_in[20];

    const int* idx_i = pidx;
    const int* idx_j = pidx + NPAIRS;

    float* outp = (float*)d_out;
    float* pred = outp;                        // [N,2]
    float* v    = outp + (size_t)NATOMS * 2;   // [N,128]

    const size_t NF = (size_t)NATOMS * F;
    float* u = (float*)d_ws;                          // [N,F] fp32
    unsigned short* mj = (unsigned short*)(u + NF);   // [N,F] bf16
    short* wpack = (short*)(mj + NF);                 // 13*16384 bf16
    int* counts   = (int*)(wpack + 13 * 16384);
    int* offsets  = counts + NATOMS;
    int* cursor   = offsets + NATOMS + 1;
    int* plist    = cursor + NATOMS;
    int* jlist    = plist + NPAIRS;
    int* bsum     = jlist + NPAIRS;
    int* bbase    = bsum + NBLK;

    const short* wpWi = wpack;
    const short* wpWj = wpack + 1 * 16384;
    const short* wpWv = wpack + 2 * 16384;
    const short* wpI1 = wpack + 3 * 16384;   // 3 mats
    const short* wpI2 = wpack + 6 * 16384;   // 3 mats
    const short* wpO1 = wpack + 9 * 16384;   // 2 mats
    const short* wpO2 = wpack + 11 * 16384;  // 2 mats

    // weight prepack + CSR build
    prep_w_k<<<(13 * 16384 + 255) / 256, 256, 0, stream>>>(Wi, Wj, Wv, iW1, iW2, oW1, oW2, wpack);
    hipMemsetAsync(counts, 0, NATOMS * sizeof(int), stream);
    hist_k<<<(NPAIRS + 255) / 256, 256, 0, stream>>>(idx_i, counts);
    scan1_k<<<NBLK, 256, 0, stream>>>(counts, bsum);
    scan2_k<<<1, 256, 0, stream>>>(bsum, bbase, offsets);
    scan3_k<<<NBLK, 256, 0, stream>>>(counts, bbase, offsets, cursor);
    scatter_k<<<(NPAIRS + 255) / 256, 256, 0, stream>>>(idx_i, idx_j, cursor, plist, jlist);

    // u = sp(sp(emb)@Wi+bi); mj = bf16(sp(sp(emb)@Wj+bj))   (32 rows/block)
    mgemm_k<1, 1, 1><<<(NATOMS + 31) / 32, 256, 0, stream>>>(
        emb, wpWi, bi, u, wpWj, bj, mj, NATOMS);

    // u[i] += mj[j] * (fij @ Wg), one wave per atom, 8-deep batches
    gather_k<<<(NATOMS + 3) / 4, 256, 0, stream>>>(
        mj, fij, jlist, plist, offsets, Wg, u);

    // fused tail: 3 int res + Wv combine + 2 out res + pred (32 rows/block)
    fused_tail_k<<<(NATOMS + 31) / 32, 256, 0, stream>>>(
        u, emb, gate,
        wpI1, ib1, wpI2, ib2,
        wpWv, bv,
        wpO1, ob1, wpO2, ob2,
        Wo, bo, v, pred, NATOMS);
}